// Round 16
// baseline (198.897 us; speedup 1.0000x reference)
//
#include <hip/hip_runtime.h>
#include <hip/hip_bf16.h>

typedef __bf16 bf16_t;
typedef __bf16 bf16x8 __attribute__((ext_vector_type(8)));
typedef float f32x4 __attribute__((ext_vector_type(4)));
typedef short short4v __attribute__((ext_vector_type(4)));
typedef unsigned int uint2v __attribute__((ext_vector_type(2)));

#define D_MODEL 1024
#define T_SEQ 2048
#define NH 16
#define DKD 64
#define X_ELEMS (4194304u)   // 2*2048*1024
#define W_ELEMS (1048576u)   // 1024*1024
// 0.125 * log2(e): folds the 1/sqrt(dk) scale AND the exp->exp2 conversion into Q
#define Q_SCALE 0.18033688011112042f

__device__ __forceinline__ void async16(const bf16_t* g, bf16_t* l) {
    __builtin_amdgcn_global_load_lds((const __attribute__((address_space(1))) void*)g,
                                     (__attribute__((address_space(3))) void*)l, 16, 0, 0);
}

__device__ __forceinline__ unsigned ldsa(const bf16_t* p) {
    return (unsigned)(size_t)(const __attribute__((address_space(3))) bf16_t*)p;
}

// ---------------- fused: fp32->bf16 convert + rope tables ----------------
// blocks [0,8192): convert x + 4 weights; [8192,8448): rope cos/sin [T][32].
__global__ __launch_bounds__(256) void convert_kernel(
    const float* __restrict__ x, const float* __restrict__ wq,
    const float* __restrict__ wk, const float* __restrict__ wv,
    const float* __restrict__ wo,
    bf16_t* __restrict__ xb, bf16_t* __restrict__ wqb, bf16_t* __restrict__ wkb,
    bf16_t* __restrict__ wvb, bf16_t* __restrict__ wob,
    float* __restrict__ cost, float* __restrict__ sint)
{
    const unsigned bid = blockIdx.x;
    if (bid < 8192) {
        size_t idx = ((size_t)bid * 256 + threadIdx.x) * 4;
        const float* src; bf16_t* dst; size_t off;
        if (idx < X_ELEMS) { src = x; dst = xb; off = idx; }
        else {
            size_t r = idx - X_ELEMS;
            unsigned w = (unsigned)(r >> 20);
            off = r & (W_ELEMS - 1);
            src = (w == 0) ? wq : (w == 1) ? wk : (w == 2) ? wv : wo;
            dst = (w == 0) ? wqb : (w == 1) ? wkb : (w == 2) ? wvb : wob;
        }
        float4 v = *(const float4*)(src + off);
        union { bf16_t b[4]; short4v s; } u;
        u.b[0] = (bf16_t)v.x; u.b[1] = (bf16_t)v.y;
        u.b[2] = (bf16_t)v.z; u.b[3] = (bf16_t)v.w;
        *(short4v*)(dst + off) = u.s;
    } else {
        int idx = (int)(bid - 8192) * 256 + threadIdx.x;  // < 2048*32
        int t = idx >> 5, i = idx & 31;
        float inv = expf(-0.28782313662425572f * (float)i);  // 10000^(-i/32)
        float ang = (float)t * inv;
        float s, c;
        sincosf(ang, &s, &c);
        cost[idx] = c; sint[idx] = s;
    }
}

// ---------------- QKV GEMM: BM=128 x BN=64 -> 1536 blocks = 6 blocks/CU ----------------
// R14 post-mortem: revert verified (QKV 45.9us exactly, R7 signature); out_proj's
// 1->2 blocks/CU occupancy lever gained ~6us total. Session meta-lesson: schedule
// grafts fail (R7/R8/R9 ledger), occupancy levers win (R6 attn, R11 out_proj).
// Applying it to QKV: BN 128->64 doubles co-resident blocks (3->6/CU) so blocks
// hide each other's vmcnt drains. Same single-buffer 2-barrier frame (untouched
// schedule). Bonus: BN=64 lets mode 2 drop the operand swap — unswapped C[m,n]
// writes V^T as PACKED u64 (reg dim = 4 consecutive t), one uniform path.
// mode 0: Q out (rope, *Q_SCALE)  mode 1: K out (rope)  mode 2: V^T out (B,H,DK,T)
__global__ __launch_bounds__(256) void qkv_gemm(
    const bf16_t* __restrict__ A,
    const bf16_t* __restrict__ W0, const bf16_t* __restrict__ W1, const bf16_t* __restrict__ W2,
    bf16_t* __restrict__ qout, bf16_t* __restrict__ kout, bf16_t* __restrict__ vout,
    const float* __restrict__ cost, const float* __restrict__ sint)
{
    const int K = 1024;
    __shared__ bf16_t As[128 * 32];
    __shared__ bf16_t Bs[64 * 32];
    const int tid = threadIdx.x;
    const int wave = tid >> 6, lane = tid & 63;
    const int quad = lane >> 4, l16 = lane & 15;
    const int m0 = blockIdx.x * 128;
    const int n0 = blockIdx.y * 64;
    const int wm = (wave >> 1) * 64, wn = (wave & 1) * 32;
    const int mode = blockIdx.z;
    const bf16_t* W = (mode == 1) ? W1 : (mode == 2) ? W2 : W0;

    const f32x4 fzero = {0.f, 0.f, 0.f, 0.f};
    f32x4 acc[4][2];
    #pragma unroll
    for (int i = 0; i < 4; ++i)
        #pragma unroll
        for (int j = 0; j < 2; ++j) acc[i][j] = fzero;

    for (int k0 = 0; k0 < K; k0 += 32) {
        __syncthreads();
        #pragma unroll
        for (int c = 0; c < 2; ++c) {
            int G = c * 256 + tid;
            int row = G >> 2, go = G & 3;
            async16(A + (size_t)(m0 + row) * K + (k0 + go * 8), As + (size_t)(c * 256 + wave * 64) * 8);
        }
        {
            int row = tid >> 2, go = tid & 3;
            async16(W + (size_t)(n0 + row) * K + (k0 + go * 8), Bs + (size_t)(wave * 64) * 8);
        }
        __syncthreads();
        bf16x8 af[4], bfv[2];
        #pragma unroll
        for (int mi = 0; mi < 4; ++mi)
            af[mi] = *(const bf16x8*)(As + (wm + mi * 16 + l16) * 32 + quad * 8);
        #pragma unroll
        for (int ni = 0; ni < 2; ++ni)
            bfv[ni] = *(const bf16x8*)(Bs + (wn + ni * 16 + l16) * 32 + quad * 8);
        #pragma unroll
        for (int mi = 0; mi < 4; ++mi)
            #pragma unroll
            for (int ni = 0; ni < 2; ++ni)
                acc[mi][ni] = __builtin_amdgcn_mfma_f32_16x16x32_bf16(af[mi], bfv[ni], acc[mi][ni], 0, 0, 0);
    }

    #pragma unroll
    for (int mi = 0; mi < 4; ++mi) {
        #pragma unroll
        for (int ni = 0; ni < 2; ++ni) {
            if (mode == 2) {
                // V^T: rows (m=tok) are the reg dim -> 4 consecutive t, pack u64
                int col = n0 + wn + ni * 16 + l16;          // f
                int row0 = m0 + wm + mi * 16 + quad * 4;     // tok base
                int t0 = row0 & (T_SEQ - 1), b = row0 >> 11;
                int h = col >> 6, dk = col & 63;
                union { bf16_t hh[4]; unsigned long long u64; } pk;
                #pragma unroll
                for (int reg = 0; reg < 4; ++reg) pk.hh[reg] = (bf16_t)acc[mi][ni][reg];
                *(unsigned long long*)(vout + (((size_t)b * NH + h) * DKD + dk) * T_SEQ + t0) = pk.u64;
            } else {
                #pragma unroll
                for (int reg = 0; reg < 4; ++reg) {
                    float v = acc[mi][ni][reg];
                    int row = m0 + wm + mi * 16 + quad * 4 + reg;
                    int col = n0 + wn + ni * 16 + l16;
                    int t = row & (T_SEQ - 1), b = row >> 11;
                    int h = col >> 6, dk = col & 63;
                    float vp = __shfl_xor(v, 1);
                    int fi = dk >> 1;
                    float c = cost[t * 32 + fi], s = sint[t * 32 + fi];
                    float r = (dk & 1) ? (vp * s + v * c) : (v * c - vp * s);
                    if (mode == 0) r *= Q_SCALE;   // fold 1/sqrt(dk)*log2e into Q
                    bf16_t* dst = (mode == 0) ? qout : kout;
                    dst[(((size_t)b * NH + h) * T_SEQ + t) * DKD + dk] = (bf16_t)r;
                }
            }
        }
    }
}

// ---------------- out-proj GEMM: separate kernel, 64x128 tile -> 512 blocks = 2/CU ----------------
// (unchanged — verified <45.9us in R14, worth ~6us of total vs 1 block/CU.)
__global__ __launch_bounds__(256) void out_proj(
    const bf16_t* __restrict__ A, const bf16_t* __restrict__ W,
    float* __restrict__ fout)
{
    const int K = 1024;
    __shared__ bf16_t As[64 * 32];
    __shared__ bf16_t Bs[128 * 32];
    const int tid = threadIdx.x;
    const int wave = tid >> 6, lane = tid & 63;
    const int quad = lane >> 4, l16 = lane & 15;
    const int m0 = blockIdx.x * 64;
    const int n0 = blockIdx.y * 128;
    const int wm = (wave >> 1) * 32, wn = (wave & 1) * 64;

    const f32x4 fzero = {0.f, 0.f, 0.f, 0.f};
    f32x4 acc[2][4];
    #pragma unroll
    for (int i = 0; i < 2; ++i)
        #pragma unroll
        for (int j = 0; j < 4; ++j) acc[i][j] = fzero;

    const int arow = tid >> 2, ago = tid & 3;

    for (int k0 = 0; k0 < K; k0 += 32) {
        __syncthreads();
        async16(A + (size_t)(m0 + arow) * K + (k0 + ago * 8), As + (size_t)(wave * 64) * 8);
        #pragma unroll
        for (int c = 0; c < 2; ++c) {
            int G = c * 256 + tid;
            int row = G >> 2, go = G & 3;
            async16(W + (size_t)(n0 + row) * K + (k0 + go * 8), Bs + (size_t)(c * 256 + wave * 64) * 8);
        }
        __syncthreads();
        bf16x8 af[2], bfv[4];
        #pragma unroll
        for (int mi = 0; mi < 2; ++mi)
            af[mi] = *(const bf16x8*)(As + (wm + mi * 16 + l16) * 32 + quad * 8);
        #pragma unroll
        for (int ni = 0; ni < 4; ++ni)
            bfv[ni] = *(const bf16x8*)(Bs + (wn + ni * 16 + l16) * 32 + quad * 8);
        #pragma unroll
        for (int mi = 0; mi < 2; ++mi)
            #pragma unroll
            for (int ni = 0; ni < 4; ++ni)
                acc[mi][ni] = __builtin_amdgcn_mfma_f32_16x16x32_bf16(af[mi], bfv[ni], acc[mi][ni], 0, 0, 0);
    }

    #pragma unroll
    for (int mi = 0; mi < 2; ++mi) {
        #pragma unroll
        for (int ni = 0; ni < 4; ++ni) {
            #pragma unroll
            for (int reg = 0; reg < 4; ++reg) {
                int row = m0 + wm + mi * 16 + quad * 4 + reg;
                int col = n0 + wn + ni * 16 + l16;
                fout[(size_t)row * D_MODEL + col] = acc[mi][ni][reg];
            }
        }
    }
}

// ---------------- flash attention v3: 4-wave blocks, shared K+V LDS staging ----------------
// (unchanged — one change-set per measurement.)
__global__ __launch_bounds__(256, 4) void attn_kernel(
    const bf16_t* __restrict__ Q, const bf16_t* __restrict__ Kb,
    const bf16_t* __restrict__ Vt, bf16_t* __restrict__ O,
    float* __restrict__ Opart, float* __restrict__ Lpart)
{
    __shared__ bf16_t Vs[2][4096];   // 16 KB: V^T tiles (64d x 64key), swizzled
    __shared__ bf16_t Ks[2][4096];   // 16 KB: K tiles (64key x 64dk), swizzled
    const int tid = threadIdx.x;
    const int w = tid >> 6;          // wave id = q-subtile id
    const int lane = tid & 63;
    const int quad = lane >> 4, l16 = lane & 15;
    const int sig = ((quad & 1) << 1) | (quad >> 1);   // sigma(quad)
    const int m7 = l16 & 7;
    const int bh = blockIdx.x;

    // map blockIdx.y (reversed: heavy g first) -> (g, c); po = chunk prefix among g>=4
    int v = 39 - (int)blockIdx.y;
    int g = 0, po = 0;
    for (;; ++g) {
        const int C = (g + 4) >> 2;
        if (v < C) break;
        v -= C;
        if (g >= 4) po += C;
    }
    const int c = v;
    const int ktlo = 8 * c;
    const int kthi = min(8 * c + 8, 2 * g + 2);   // nktmax(g) = 2g+2 exactly
    const int qw = (4 * g + w) * 32;

    const bf16_t* kbase = Kb + (size_t)bh * T_SEQ * DKD;
    const bf16_t* vbase = Vt + (size_t)bh * DKD * T_SEQ;

    // cooperative staging: thread covers row srow=(tid>>3) (+32 per call),
    // source granule pre-swizzled (inverse of LDS[r][s] = global granule s^(r&7))
    const int srow = tid >> 3;
    const int sgr  = (tid & 7) ^ (srow & 7);
    const bf16_t* vsrc = vbase + (size_t)srow * T_SEQ + sgr * 8;   // V^T rows = d
    const bf16_t* ksrc = kbase + (size_t)srow * DKD + sgr * 8;     // K rows = key

    // swizzled ds_read byte offsets (lane-constant; +di/fi*2048 via imm)
    const unsigned o0  = (unsigned)((l16 * 64 + ((sig ^ m7) * 8)) << 1);        // V keys [0,32)
    const unsigned o1  = (unsigned)((l16 * 64 + (((sig + 4) ^ m7) * 8)) << 1);  // V keys [32,64)
    const unsigned ko0 = (unsigned)((l16 * 64 + ((quad ^ m7) * 8)) << 1);       // K dk [0,32)
    const unsigned ko1 = (unsigned)((l16 * 64 + (((quad + 4) ^ m7) * 8)) << 1); // K dk [32,64)
    const unsigned vb0 = ldsa(Vs[0]), vb1 = ldsa(Vs[1]);
    const unsigned kb0 = ldsa(Ks[0]), kb1 = ldsa(Ks[1]);

    // Q^T B-frags: n=l16 (query), k=quad*8 (+32)
    bf16x8 qf[2][2];
    #pragma unroll
    for (int j = 0; j < 2; ++j) {
        const bf16_t* qp = Q + ((size_t)bh * T_SEQ + qw + j * 16 + l16) * DKD;
        qf[j][0] = *(const bf16x8*)(qp + quad * 8);
        qf[j][1] = *(const bf16x8*)(qp + 32 + quad * 8);
    }
    const f32x4 fzero = {0.f, 0.f, 0.f, 0.f};
    f32x4 oacc[2][4];
    #pragma unroll
    for (int j = 0; j < 2; ++j)
        #pragma unroll
        for (int i = 0; i < 4; ++i) oacc[j][i] = fzero;
    float lsum[2] = {0.f, 0.f};

    // prologue: stage K(ktlo)+V(ktlo) into buf0; drain own DMA; barrier.
    {
        const bf16_t* vs_ = vsrc + ktlo * 64;
        const bf16_t* ks_ = ksrc + (size_t)ktlo * 64 * DKD;
        async16(vs_,         &Vs[0][0] + w * 512);
        async16(vs_ + 65536, &Vs[0][0] + 2048 + w * 512);
        async16(ks_,         &Ks[0][0] + w * 512);
        async16(ks_ + 2048,  &Ks[0][0] + 2048 + w * 512);
    }
    asm volatile("s_waitcnt vmcnt(0)" ::: "memory");
    __syncthreads();

#define ATT_TILE(VNP, KNP, VCA, KCA) do { \
    const int k0 = kt * 64; \
    if (kt + 1 < kthi) { \
        const bf16_t* vs_ = vsrc + (k0 + 64); \
        const bf16_t* ks_ = ksrc + (size_t)(k0 + 64) * DKD; \
        async16(vs_,         (VNP) + w * 512); \
        async16(vs_ + 65536, (VNP) + 2048 + w * 512); \
        async16(ks_,         (KNP) + w * 512); \
        async16(ks_ + 2048,  (KNP) + 2048 + w * 512); \
    } \
    __builtin_amdgcn_sched_barrier(0); \
    bf16x8 kc00, kc01, kc10, kc11, kc20, kc21, kc30, kc31; \
    { const unsigned kaA = (KCA) + ko0, kaB = (KCA) + ko1; \
      asm volatile( \
        "ds_read_b128 %0, %8 offset:0\n\t" \
        "ds_read_b128 %1, %9 offset:0\n\t" \
        "ds_read_b128 %2, %8 offset:2048\n\t" \
        "ds_read_b128 %3, %9 offset:2048\n\t" \
        "ds_read_b128 %4, %8 offset:4096\n\t" \
        "ds_read_b128 %5, %9 offset:4096\n\t" \
        "ds_read_b128 %6, %8 offset:6144\n\t" \
        "ds_read_b128 %7, %9 offset:6144\n\t" \
        "s_waitcnt lgkmcnt(0)" \
        : "=&v"(kc00), "=&v"(kc01), "=&v"(kc10), "=&v"(kc11), \
          "=&v"(kc20), "=&v"(kc21), "=&v"(kc30), "=&v"(kc31) \
        : "v"(kaA), "v"(kaB)); } \
    __builtin_amdgcn_sched_barrier(0); \
    _Pragma("unroll") \
    for (int j = 0; j < 2; ++j) { \
      if (k0 <= qw + j * 16 + 15) {   /* else q-tile fully masked */ \
        const int qcol = qw + j * 16 + l16; \
        f32x4 s[4]; \
        s[0] = __builtin_amdgcn_mfma_f32_16x16x32_bf16(kc00, qf[j][0], fzero, 0, 0, 0); \
        s[0] = __builtin_amdgcn_mfma_f32_16x16x32_bf16(kc01, qf[j][1], s[0], 0, 0, 0); \
        s[1] = __builtin_amdgcn_mfma_f32_16x16x32_bf16(kc10, qf[j][0], fzero, 0, 0, 0); \
        s[1] = __builtin_amdgcn_mfma_f32_16x16x32_bf16(kc11, qf[j][1], s[1], 0, 0, 0); \
        s[2] = __builtin_amdgcn_mfma_f32_16x16x32_bf16(kc20, qf[j][0], fzero, 0, 0, 0); \
        s[2] = __builtin_amdgcn_mfma_f32_16x16x32_bf16(kc21, qf[j][1], s[2], 0, 0, 0); \
        s[3] = __builtin_amdgcn_mfma_f32_16x16x32_bf16(kc30, qf[j][0], fzero, 0, 0, 0); \
        s[3] = __builtin_amdgcn_mfma_f32_16x16x32_bf16(kc31, qf[j][1], s[3], 0, 0, 0); \
        if (k0 + 63 > qw + j * 16) { \
            _Pragma("unroll") \
            for (int fi = 0; fi < 4; ++fi) \
                _Pragma("unroll") \
                for (int reg = 0; reg < 4; ++reg) { \
                    int key = k0 + fi * 16 + quad * 4 + reg; \
                    s[fi][reg] = (key > qcol) ? -__builtin_inff() : s[fi][reg]; \
                } \
        } \
        float sm = 0.f; \
        _Pragma("unroll") \
        for (int fi = 0; fi < 4; ++fi) \
            _Pragma("unroll") \
            for (int reg = 0; reg < 4; ++reg) { \
                float p = __builtin_amdgcn_exp2f(s[fi][reg]); \
                s[fi][reg] = p; sm += p; \
            } \
        lsum[j] += sm; \
        unsigned wv[4][2]; \
        _Pragma("unroll") \
        for (int fi = 0; fi < 4; ++fi) { \
            asm("v_cvt_pk_bf16_f32 %0, %1, %2" : "=v"(wv[fi][0]) : "v"(s[fi][0]), "v"(s[fi][1])); \
            asm("v_cvt_pk_bf16_f32 %0, %1, %2" : "=v"(wv[fi][1]) : "v"(s[fi][2]), "v"(s[fi][3])); \
        } \
        uint2v r0 = __builtin_amdgcn_permlane16_swap(wv[0][0], wv[1][0], false, false); \
        uint2v r1 = __builtin_amdgcn_permlane16_swap(wv[0][1], wv[1][1], false, false); \
        uint2v r2 = __builtin_amdgcn_permlane16_swap(wv[2][0], wv[3][0], false, false); \
        uint2v r3 = __builtin_amdgcn_permlane16_swap(wv[2][1], wv[3][1], false, false); \
        union { unsigned uu[4]; bf16x8 vv; } p0, p1; \
        p0.uu[0] = r0[0]; p0.uu[1] = r1[0]; p0.uu[2] = r0[1]; p0.uu[3] = r1[1]; \
        p1.uu[0] = r2[0]; p1.uu[1] = r3[0]; p1.uu[2] = r2[1]; p1.uu[3] = r3[1]; \
        const unsigned vA = (VCA) + o0, vB = (VCA) + o1; \
        bf16x8 w0a, w0b, w1a, w1b; \
        __builtin_amdgcn_sched_barrier(0); \
        asm volatile( \
            "ds_read_b128 %0, %4 offset:0\n\t" \
            "ds_read_b128 %1, %5 offset:0\n\t" \
            "ds_read_b128 %2, %4 offset:2048\n\t" \
            "ds_read_b128 %3, %5 offset:2048\n\t" \
            "s_waitcnt lgkmcnt(0)" \
            : "=&v"(w0a), "=&v"(w0b), "=&v"(w1a), "=&v"(w1b) \
            : "v"(vA), "v"(vB)); \
        __builtin_amdgcn_sched_barrier(0); \
        oacc[j][0] = __builtin_amdgcn_mfma_f32_16x16x32_bf16(w0a, p0.vv, oacc[j][0], 0, 0, 0); \
        oacc[j][0] = __builtin_amdgcn_mfma_f32_16x16x32_bf16(w0b, p1.vv, oacc[j][0], 0, 0, 0); \
        oacc[j][1] = __builtin_amdgcn_mfma_f32_16x16x32_bf16(w1a, p0.vv, oacc[j][1], 0, 0, 0); \
        oacc[j][1] = __builtin_amdgcn_mfma_f32_16x16x32_bf16(w1b, p1.vv, oacc[j][1], 0, 0, 0); \
        bf16x8 w2a, w2b, w3a, w3b; \
        asm volatile( \
            "ds_read_b128 %0, %4 offset:4096\n\t" \
            "ds_read_b128 %1, %5 offset:4096\n\t" \
            "ds_read_b128 %2, %4 offset:6144\n\t" \
            "ds_read_b128 %3, %5 offset:6144\n\t" \
            "s_waitcnt lgkmcnt(0)" \
            : "=&v"(w2a), "=&v"(w2b), "=&v"(w3a), "=&v"(w3b) \
            : "v"(vA), "v"(vB)); \
        __builtin_amdgcn_sched_barrier(0); \
        oacc[j][2] = __builtin_amdgcn_mfma_f32_16x16x32_bf16(w2a, p0.vv, oacc[j][2], 0, 0, 0); \
        oacc[j][2] = __builtin_amdgcn_mfma_f32_16x16x32_bf16(w2b, p1.vv, oacc[j][2], 0, 0, 0); \
        oacc[j][3] = __builtin_amdgcn_mfma_f32_16x16x32_bf16(w3a, p0.vv, oacc[j][3], 0, 0, 0); \
        oacc[j][3] = __builtin_amdgcn_mfma_f32_16x16x32_bf16(w3b, p1.vv, oacc[j][3], 0, 0, 0); \
      } \
    } \
    asm volatile("s_waitcnt vmcnt(0)" ::: "memory"); \
    __syncthreads(); \
} while (0)

    bool flip = false;
    for (int kt = ktlo; kt < kthi; ++kt) {
        if (!flip) { ATT_TILE(&Vs[1][0], &Ks[1][0], vb0, kb0); }
        else       { ATT_TILE(&Vs[0][0], &Ks[0][0], vb1, kb1); }
        flip = !flip;
    }
#undef ATT_TILE

    if (g < 4) {
        // single-chunk: cross-quad l reduction, scale, store bf16 directly
        const int b = bh >> 4, h = bh & 15;
        #pragma unroll
        for (int j = 0; j < 2; ++j) {
            float l = lsum[j];
            l += __shfl_xor(l, 16);
            l += __shfl_xor(l, 32);
            float rl = 1.0f / l;
            int q = qw + j * 16 + l16;
            #pragma unroll
            for (int di = 0; di < 4; ++di) {
                union { bf16_t hh[4]; unsigned long long u64; } ok;
                #pragma unroll
                for (int reg = 0; reg < 4; ++reg) ok.hh[reg] = (bf16_t)(oacc[j][di][reg] * rl);
                int d = di * 16 + quad * 4;
                *(unsigned long long*)(O + ((size_t)b * T_SEQ + q) * D_MODEL + h * DKD + d) = ok.u64;
            }
        }
    } else {
        // partial: raw fp32 oacc + per-lane lsum to workspace
        const size_t slot = (size_t)bh * 36 + po + c;
        float* op = Opart + slot * 8192 + (size_t)w * 2048;
        #pragma unroll
        for (int j = 0; j < 2; ++j) {
            Lpart[slot * 512 + w * 128 + j * 64 + lane] = lsum[j];
            #pragma unroll
            for (int di = 0; di < 4; ++di)
                *(f32x4*)(op + ((size_t)(j * 4 + di) * 64 + lane) * 4) = oacc[j][di];
        }
    }
}

// ---------------- combine: O = (sum_c O_c) / (sum_c l_c), q rows [512, 2048) ----------------
__global__ __launch_bounds__(256) void combine_kernel(
    const float* __restrict__ Opart, const float* __restrict__ Lpart, bf16_t* __restrict__ O)
{
    const int bh = blockIdx.x;
    const int g = 4 + blockIdx.y;            // 4..15
    const int C = (g + 4) >> 2;              // chunks for this g
    int po0 = 0;
    for (int gg = 4; gg < g; ++gg) po0 += (gg + 4) >> 2;
    const int t = threadIdx.x;
    const int ql = t >> 3;                   // 0..31 local query
    const int d0 = (t & 7) * 8;              // 0,8,...,56
    const int j = ql >> 4, l16 = ql & 15;
    const int di = d0 >> 4;
    const int quad0 = (d0 & 15) >> 2;        // 0 or 2
    const int b = bh >> 4, h = bh & 15;
    const size_t sb = (size_t)bh * 36 + po0;

    for (int w = 0; w < 4; ++w) {
        float l = 0.f;
        for (int cc = 0; cc < C; ++cc) {
            const float* L = Lpart + (sb + cc) * 512 + w * 128 + j * 64 + l16;
            #pragma unroll
            for (int q = 0; q < 4; ++q) l += L[q * 16];
        }
        const float rl = 1.0f / l;
        union { bf16_t hh[8]; bf16x8 vv; } ov;
        #pragma unroll
        for (int g2 = 0; g2 < 2; ++g2) {
            const int off = ((j * 4 + di) * 64 + (quad0 + g2) * 16 + l16) * 4;
            f32x4 acc = {0.f, 0.f, 0.f, 0.f};
            for (int cc = 0; cc < C; ++cc)
                acc += *(const f32x4*)(Opart + (sb + cc) * 8192 + (size_t)w * 2048 + off);
            #pragma unroll
            for (int reg = 0; reg < 4; ++reg)
                ov.hh[g2 * 4 + reg] = (bf16_t)(acc[reg] * rl);
        }
        const int q = g * 128 + w * 32 + ql;
        *(bf16x8*)(O + ((size_t)b * T_SEQ + q) * D_MODEL + h * DKD + d0) = ov.vv;
    }
}

extern "C" void kernel_launch(void* const* d_in, const int* in_sizes, int n_in,
                              void* d_out, int out_size, void* d_ws, size_t ws_size,
                              hipStream_t stream)
{
    const float* x  = (const float*)d_in[0];
    const float* wq = (const float*)d_in[1];
    const float* wk = (const float*)d_in[2];
    const float* wv = (const float*)d_in[3];
    const float* wo = (const float*)d_in[4];
    float* out = (float*)d_out;

    char* ws = (char*)d_ws;
    size_t off = 0;
    auto alloc = [&](size_t bytes) -> void* {
        void* p = ws + off; off += (bytes + 255) & ~(size_t)255; return p;
    };
    bf16_t* xb   = (bf16_t*)alloc((size_t)X_ELEMS * 2);
    bf16_t* wqb  = (bf16_t*)alloc((size_t)W_ELEMS * 2);
    bf16_t* wkb  = (bf16_t*)alloc((size_t)W_ELEMS * 2);
    bf16_t* wvb  = (bf16_t*)alloc((size_t)W_ELEMS * 2);
    bf16_t* wob  = (bf16_t*)alloc((size_t)W_ELEMS * 2);
    bf16_t* qb   = (bf16_t*)alloc((size_t)X_ELEMS * 2);
    bf16_t* kb   = (bf16_t*)alloc((size_t)X_ELEMS * 2);
    bf16_t* vtb  = (bf16_t*)alloc((size_t)X_ELEMS * 2);
    bf16_t* ob   = (bf16_t*)alloc((size_t)X_ELEMS * 2);
    float*  cost = (float*)alloc((size_t)T_SEQ * 32 * 4);
    float*  sint = (float*)alloc((size_t)T_SEQ * 32 * 4);
    float*  opart = (float*)alloc((size_t)32 * 36 * 8192 * 4);  // 1152 slots x 4w x 32q x 64d fp32
    float*  lpart = (float*)alloc((size_t)32 * 36 * 512 * 4);   // 1152 slots x 4w x 2j x 64 lanes

    // convert (8192) + rope (256) fused into one launch
    convert_kernel<<<8448, 256, 0, stream>>>(x, wq, wk, wv, wo, xb, wqb, wkb, wvb, wob,
                                             cost, sint);
    // QKV: 128x64 tiles -> 1536 blocks = 6 blocks/CU (was 768 = 3/CU)
    qkv_gemm<<<dim3(32, 16, 3), 256, 0, stream>>>(xb, wqb, wkb, wvb, qb, kb, vtb, cost, sint);
    attn_kernel<<<dim3(32, 40), 256, 0, stream>>>(qb, kb, vtb, ob, opart, lpart);
    combine_kernel<<<dim3(32, 12), 256, 0, stream>>>(opart, lpart, ob);
    // out-proj: 64x128 tiles -> 512 blocks = 2 blocks/CU
    out_proj<<<dim3(64, 8), 256, 0, stream>>>(ob, wob, out);
}

// Round 20
// 196.349 us; speedup vs baseline: 1.0130x; 1.0130x over previous
//
#include <hip/hip_runtime.h>
#include <hip/hip_bf16.h>

typedef __bf16 bf16_t;
typedef __bf16 bf16x8 __attribute__((ext_vector_type(8)));
typedef float f32x4 __attribute__((ext_vector_type(4)));
typedef short short4v __attribute__((ext_vector_type(4)));
typedef unsigned int uint2v __attribute__((ext_vector_type(2)));

#define D_MODEL 1024
#define T_SEQ 2048
#define NH 16
#define DKD 64
#define X_ELEMS (4194304u)   // 2*2048*1024
#define W_ELEMS (1048576u)   // 1024*1024
// 0.125 * log2(e): folds the 1/sqrt(dk) scale AND the exp->exp2 conversion into Q
#define Q_SCALE 0.18033688011112042f

__device__ __forceinline__ void async16(const bf16_t* g, bf16_t* l) {
    __builtin_amdgcn_global_load_lds((const __attribute__((address_space(1))) void*)g,
                                     (__attribute__((address_space(3))) void*)l, 16, 0, 0);
}

__device__ __forceinline__ unsigned ldsa(const bf16_t* p) {
    return (unsigned)(size_t)(const __attribute__((address_space(3))) bf16_t*)p;
}

// ---------------- fused: fp32->bf16 convert + rope tables ----------------
// blocks [0,8192): convert x + 4 weights; [8192,8448): rope cos/sin [T][32].
__global__ __launch_bounds__(256) void convert_kernel(
    const float* __restrict__ x, const float* __restrict__ wq,
    const float* __restrict__ wk, const float* __restrict__ wv,
    const float* __restrict__ wo,
    bf16_t* __restrict__ xb, bf16_t* __restrict__ wqb, bf16_t* __restrict__ wkb,
    bf16_t* __restrict__ wvb, bf16_t* __restrict__ wob,
    float* __restrict__ cost, float* __restrict__ sint)
{
    const unsigned bid = blockIdx.x;
    if (bid < 8192) {
        size_t idx = ((size_t)bid * 256 + threadIdx.x) * 4;
        const float* src; bf16_t* dst; size_t off;
        if (idx < X_ELEMS) { src = x; dst = xb; off = idx; }
        else {
            size_t r = idx - X_ELEMS;
            unsigned w = (unsigned)(r >> 20);
            off = r & (W_ELEMS - 1);
            src = (w == 0) ? wq : (w == 1) ? wk : (w == 2) ? wv : wo;
            dst = (w == 0) ? wqb : (w == 1) ? wkb : (w == 2) ? wvb : wob;
        }
        float4 v = *(const float4*)(src + off);
        union { bf16_t b[4]; short4v s; } u;
        u.b[0] = (bf16_t)v.x; u.b[1] = (bf16_t)v.y;
        u.b[2] = (bf16_t)v.z; u.b[3] = (bf16_t)v.w;
        *(short4v*)(dst + off) = u.s;
    } else {
        int idx = (int)(bid - 8192) * 256 + threadIdx.x;  // < 2048*32
        int t = idx >> 5, i = idx & 31;
        float inv = expf(-0.28782313662425572f * (float)i);  // 10000^(-i/32)
        float ang = (float)t * inv;
        float s, c;
        sincosf(ang, &s, &c);
        cost[idx] = c; sint[idx] = s;
    }
}

// ---------------- QKV GEMM (measured-best frame; byte-for-byte R7/R14 text) ----------------
// FINAL LEDGER (all measured on this problem, QKV dispatch):
//   45.9us  single-buffer BK32 128x128 (THIS)        <- floor
//   47.1us  double-buffer 2-phase
//   50.0us  BN=64 (6 blocks/CU: occupancy 25->29 only; per-drain MFMA halved)
//   53.6us  shared-body runtime bounds + atomic branch (rule #19 perturbation)
//   55.3us  BK=64 + XOR swizzle (T2 null at 2-phase, m252 regime gate)
//   60.3us  depth-2 counted-vmcnt 3-buffer
// Schedule grafts AND tile retuning both lose; occupancy lever wins only
// 1->2-3 blocks/CU (out_proj), loses 3->6 (BN=64). Do not touch this kernel.
// mode 0: Q out (rope, *Q_SCALE)  mode 1: K out (rope)  mode 2: V^T out (swapped)
__global__ __launch_bounds__(256) void gemm_fused(
    const bf16_t* __restrict__ A,
    const bf16_t* __restrict__ W0, const bf16_t* __restrict__ W1, const bf16_t* __restrict__ W2,
    bf16_t* __restrict__ qout, bf16_t* __restrict__ kout, bf16_t* __restrict__ vout,
    const float* __restrict__ cost, const float* __restrict__ sint,
    float* __restrict__ fout, int modeBase)
{
    const int K = 1024;
    __shared__ bf16_t As[128 * 32];
    __shared__ bf16_t Bs[128 * 32];
    const int tid = threadIdx.x;
    const int wave = tid >> 6, lane = tid & 63;
    const int quad = lane >> 4, l16 = lane & 15;
    const int m0 = blockIdx.x * 128;
    const int n0 = blockIdx.y * 128;
    const int wm = (wave >> 1) * 64, wn = (wave & 1) * 64;
    const int mode = modeBase + blockIdx.z;
    const bf16_t* W = (mode == 1) ? W1 : (mode == 2) ? W2 : W0;

    const bf16_t* Afrag = (mode == 2) ? Bs : As;
    const bf16_t* Bfrag = (mode == 2) ? As : Bs;
    const int aoff = (mode == 2) ? wn : wm;
    const int boff = (mode == 2) ? wm : wn;

    const f32x4 fzero = {0.f, 0.f, 0.f, 0.f};
    f32x4 acc[4][4];
    #pragma unroll
    for (int i = 0; i < 4; ++i)
        #pragma unroll
        for (int j = 0; j < 4; ++j) acc[i][j] = fzero;

    for (int k0 = 0; k0 < K; k0 += 32) {
        __syncthreads();
        #pragma unroll
        for (int c = 0; c < 2; ++c) {
            int G = c * 256 + tid;
            int row = G >> 2, go = G & 3;
            async16(A + (size_t)(m0 + row) * K + (k0 + go * 8), As + (size_t)(c * 256 + wave * 64) * 8);
            async16(W + (size_t)(n0 + row) * K + (k0 + go * 8), Bs + (size_t)(c * 256 + wave * 64) * 8);
        }
        __syncthreads();
        bf16x8 af[4], bfv[4];
        #pragma unroll
        for (int mi = 0; mi < 4; ++mi)
            af[mi] = *(const bf16x8*)(Afrag + (aoff + mi * 16 + l16) * 32 + quad * 8);
        #pragma unroll
        for (int ni = 0; ni < 4; ++ni)
            bfv[ni] = *(const bf16x8*)(Bfrag + (boff + ni * 16 + l16) * 32 + quad * 8);
        #pragma unroll
        for (int mi = 0; mi < 4; ++mi)
            #pragma unroll
            for (int ni = 0; ni < 4; ++ni)
                acc[mi][ni] = __builtin_amdgcn_mfma_f32_16x16x32_bf16(af[mi], bfv[ni], acc[mi][ni], 0, 0, 0);
    }

    #pragma unroll
    for (int mi = 0; mi < 4; ++mi) {
        #pragma unroll
        for (int ni = 0; ni < 4; ++ni) {
            #pragma unroll
            for (int reg = 0; reg < 4; ++reg) {
                float v = acc[mi][ni][reg];
                if (mode == 2) {
                    int f   = n0 + wn + mi * 16 + quad * 4 + reg;
                    int tok = m0 + wm + ni * 16 + l16;
                    int t = tok & (T_SEQ - 1), b = tok >> 11;
                    int h = f >> 6, dk = f & 63;
                    vout[(((size_t)b * NH + h) * DKD + dk) * T_SEQ + t] = (bf16_t)v;
                } else {
                    int row = m0 + wm + mi * 16 + quad * 4 + reg;
                    int col = n0 + wn + ni * 16 + l16;
                    if (mode == 3) {
                        fout[(size_t)row * D_MODEL + col] = v;
                    } else {
                        int t = row & (T_SEQ - 1), b = row >> 11;
                        int h = col >> 6, dk = col & 63;
                        float vp = __shfl_xor(v, 1);
                        int fi = dk >> 1;
                        float c = cost[t * 32 + fi], s = sint[t * 32 + fi];
                        float r = (dk & 1) ? (vp * s + v * c) : (v * c - vp * s);
                        if (mode == 0) r *= Q_SCALE;   // fold 1/sqrt(dk)*log2e into Q
                        bf16_t* dst = (mode == 0) ? qout : kout;
                        dst[(((size_t)b * NH + h) * T_SEQ + t) * DKD + dk] = (bf16_t)r;
                    }
                }
            }
        }
    }
}

// ---------------- out-proj GEMM: separate kernel, 64x128 tile -> 512 blocks = 2/CU ----------------
// (verified <45.9us in R14, worth ~6us of total vs 1 block/CU.)
__global__ __launch_bounds__(256) void out_proj(
    const bf16_t* __restrict__ A, const bf16_t* __restrict__ W,
    float* __restrict__ fout)
{
    const int K = 1024;
    __shared__ bf16_t As[64 * 32];
    __shared__ bf16_t Bs[128 * 32];
    const int tid = threadIdx.x;
    const int wave = tid >> 6, lane = tid & 63;
    const int quad = lane >> 4, l16 = lane & 15;
    const int m0 = blockIdx.x * 64;
    const int n0 = blockIdx.y * 128;
    const int wm = (wave >> 1) * 32, wn = (wave & 1) * 64;

    const f32x4 fzero = {0.f, 0.f, 0.f, 0.f};
    f32x4 acc[2][4];
    #pragma unroll
    for (int i = 0; i < 2; ++i)
        #pragma unroll
        for (int j = 0; j < 4; ++j) acc[i][j] = fzero;

    const int arow = tid >> 2, ago = tid & 3;

    for (int k0 = 0; k0 < K; k0 += 32) {
        __syncthreads();
        async16(A + (size_t)(m0 + arow) * K + (k0 + ago * 8), As + (size_t)(wave * 64) * 8);
        #pragma unroll
        for (int c = 0; c < 2; ++c) {
            int G = c * 256 + tid;
            int row = G >> 2, go = G & 3;
            async16(W + (size_t)(n0 + row) * K + (k0 + go * 8), Bs + (size_t)(c * 256 + wave * 64) * 8);
        }
        __syncthreads();
        bf16x8 af[2], bfv[4];
        #pragma unroll
        for (int mi = 0; mi < 2; ++mi)
            af[mi] = *(const bf16x8*)(As + (wm + mi * 16 + l16) * 32 + quad * 8);
        #pragma unroll
        for (int ni = 0; ni < 4; ++ni)
            bfv[ni] = *(const bf16x8*)(Bs + (wn + ni * 16 + l16) * 32 + quad * 8);
        #pragma unroll
        for (int mi = 0; mi < 2; ++mi)
            #pragma unroll
            for (int ni = 0; ni < 4; ++ni)
                acc[mi][ni] = __builtin_amdgcn_mfma_f32_16x16x32_bf16(af[mi], bfv[ni], acc[mi][ni], 0, 0, 0);
    }

    #pragma unroll
    for (int mi = 0; mi < 2; ++mi) {
        #pragma unroll
        for (int ni = 0; ni < 4; ++ni) {
            #pragma unroll
            for (int reg = 0; reg < 4; ++reg) {
                int row = m0 + wm + mi * 16 + quad * 4 + reg;
                int col = n0 + wn + ni * 16 + l16;
                fout[(size_t)row * D_MODEL + col] = acc[mi][ni][reg];
            }
        }
    }
}

// ---------------- flash attention v3: 4-wave blocks, shared K+V LDS staging ----------------
__global__ __launch_bounds__(256, 4) void attn_kernel(
    const bf16_t* __restrict__ Q, const bf16_t* __restrict__ Kb,
    const bf16_t* __restrict__ Vt, bf16_t* __restrict__ O,
    float* __restrict__ Opart, float* __restrict__ Lpart)
{
    __shared__ bf16_t Vs[2][4096];   // 16 KB: V^T tiles (64d x 64key), swizzled
    __shared__ bf16_t Ks[2][4096];   // 16 KB: K tiles (64key x 64dk), swizzled
    const int tid = threadIdx.x;
    const int w = tid >> 6;          // wave id = q-subtile id
    const int lane = tid & 63;
    const int quad = lane >> 4, l16 = lane & 15;
    const int sig = ((quad & 1) << 1) | (quad >> 1);   // sigma(quad)
    const int m7 = l16 & 7;
    const int bh = blockIdx.x;

    // map blockIdx.y (reversed: heavy g first) -> (g, c); po = chunk prefix among g>=4
    int v = 39 - (int)blockIdx.y;
    int g = 0, po = 0;
    for (;; ++g) {
        const int C = (g + 4) >> 2;
        if (v < C) break;
        v -= C;
        if (g >= 4) po += C;
    }
    const int c = v;
    const int ktlo = 8 * c;
    const int kthi = min(8 * c + 8, 2 * g + 2);   // nktmax(g) = 2g+2 exactly
    const int qw = (4 * g + w) * 32;

    const bf16_t* kbase = Kb + (size_t)bh * T_SEQ * DKD;
    const bf16_t* vbase = Vt + (size_t)bh * DKD * T_SEQ;

    // cooperative staging: thread covers row srow=(tid>>3) (+32 per call),
    // source granule pre-swizzled (inverse of LDS[r][s] = global granule s^(r&7))
    const int srow = tid >> 3;
    const int sgr  = (tid & 7) ^ (srow & 7);
    const bf16_t* vsrc = vbase + (size_t)srow * T_SEQ + sgr * 8;   // V^T rows = d
    const bf16_t* ksrc = kbase + (size_t)srow * DKD + sgr * 8;     // K rows = key

    // swizzled ds_read byte offsets (lane-constant; +di/fi*2048 via imm)
    const unsigned o0  = (unsigned)((l16 * 64 + ((sig ^ m7) * 8)) << 1);        // V keys [0,32)
    const unsigned o1  = (unsigned)((l16 * 64 + (((sig + 4) ^ m7) * 8)) << 1);  // V keys [32,64)
    const unsigned ko0 = (unsigned)((l16 * 64 + ((quad ^ m7) * 8)) << 1);       // K dk [0,32)
    const unsigned ko1 = (unsigned)((l16 * 64 + (((quad + 4) ^ m7) * 8)) << 1); // K dk [32,64)
    const unsigned vb0 = ldsa(Vs[0]), vb1 = ldsa(Vs[1]);
    const unsigned kb0 = ldsa(Ks[0]), kb1 = ldsa(Ks[1]);

    // Q^T B-frags: n=l16 (query), k=quad*8 (+32)
    bf16x8 qf[2][2];
    #pragma unroll
    for (int j = 0; j < 2; ++j) {
        const bf16_t* qp = Q + ((size_t)bh * T_SEQ + qw + j * 16 + l16) * DKD;
        qf[j][0] = *(const bf16x8*)(qp + quad * 8);
        qf[j][1] = *(const bf16x8*)(qp + 32 + quad * 8);
    }
    const f32x4 fzero = {0.f, 0.f, 0.f, 0.f};
    f32x4 oacc[2][4];
    #pragma unroll
    for (int j = 0; j < 2; ++j)
        #pragma unroll
        for (int i = 0; i < 4; ++i) oacc[j][i] = fzero;
    float lsum[2] = {0.f, 0.f};

    // prologue: stage K(ktlo)+V(ktlo) into buf0; drain own DMA; barrier.
    {
        const bf16_t* vs_ = vsrc + ktlo * 64;
        const bf16_t* ks_ = ksrc + (size_t)ktlo * 64 * DKD;
        async16(vs_,         &Vs[0][0] + w * 512);
        async16(vs_ + 65536, &Vs[0][0] + 2048 + w * 512);
        async16(ks_,         &Ks[0][0] + w * 512);
        async16(ks_ + 2048,  &Ks[0][0] + 2048 + w * 512);
    }
    asm volatile("s_waitcnt vmcnt(0)" ::: "memory");
    __syncthreads();

#define ATT_TILE(VNP, KNP, VCA, KCA) do { \
    const int k0 = kt * 64; \
    if (kt + 1 < kthi) { \
        const bf16_t* vs_ = vsrc + (k0 + 64); \
        const bf16_t* ks_ = ksrc + (size_t)(k0 + 64) * DKD; \
        async16(vs_,         (VNP) + w * 512); \
        async16(vs_ + 65536, (VNP) + 2048 + w * 512); \
        async16(ks_,         (KNP) + w * 512); \
        async16(ks_ + 2048,  (KNP) + 2048 + w * 512); \
    } \
    __builtin_amdgcn_sched_barrier(0); \
    bf16x8 kc00, kc01, kc10, kc11, kc20, kc21, kc30, kc31; \
    { const unsigned kaA = (KCA) + ko0, kaB = (KCA) + ko1; \
      asm volatile( \
        "ds_read_b128 %0, %8 offset:0\n\t" \
        "ds_read_b128 %1, %9 offset:0\n\t" \
        "ds_read_b128 %2, %8 offset:2048\n\t" \
        "ds_read_b128 %3, %9 offset:2048\n\t" \
        "ds_read_b128 %4, %8 offset:4096\n\t" \
        "ds_read_b128 %5, %9 offset:4096\n\t" \
        "ds_read_b128 %6, %8 offset:6144\n\t" \
        "ds_read_b128 %7, %9 offset:6144\n\t" \
        "s_waitcnt lgkmcnt(0)" \
        : "=&v"(kc00), "=&v"(kc01), "=&v"(kc10), "=&v"(kc11), \
          "=&v"(kc20), "=&v"(kc21), "=&v"(kc30), "=&v"(kc31) \
        : "v"(kaA), "v"(kaB)); } \
    __builtin_amdgcn_sched_barrier(0); \
    _Pragma("unroll") \
    for (int j = 0; j < 2; ++j) { \
      if (k0 <= qw + j * 16 + 15) {   /* else q-tile fully masked */ \
        const int qcol = qw + j * 16 + l16; \
        f32x4 s[4]; \
        s[0] = __builtin_amdgcn_mfma_f32_16x16x32_bf16(kc00, qf[j][0], fzero, 0, 0, 0); \
        s[0] = __builtin_amdgcn_mfma_f32_16x16x32_bf16(kc01, qf[j][1], s[0], 0, 0, 0); \
        s[1] = __builtin_amdgcn_mfma_f32_16x16x32_bf16(kc10, qf[j][0], fzero, 0, 0, 0); \
        s[1] = __builtin_amdgcn_mfma_f32_16x16x32_bf16(kc11, qf[j][1], s[1], 0, 0, 0); \
        s[2] = __builtin_amdgcn_mfma_f32_16x16x32_bf16(kc20, qf[j][0], fzero, 0, 0, 0); \
        s[2] = __builtin_amdgcn_mfma_f32_16x16x32_bf16(kc21, qf[j][1], s[2], 0, 0, 0); \
        s[3] = __builtin_amdgcn_mfma_f32_16x16x32_bf16(kc30, qf[j][0], fzero, 0, 0, 0); \
        s[3] = __builtin_amdgcn_mfma_f32_16x16x32_bf16(kc31, qf[j][1], s[3], 0, 0, 0); \
        if (k0 + 63 > qw + j * 16) { \
            _Pragma("unroll") \
            for (int fi = 0; fi < 4; ++fi) \
                _Pragma("unroll") \
                for (int reg = 0; reg < 4; ++reg) { \
                    int key = k0 + fi * 16 + quad * 4 + reg; \
                    s[fi][reg] = (key > qcol) ? -__builtin_inff() : s[fi][reg]; \
                } \
        } \
        float sm = 0.f; \
        _Pragma("unroll") \
        for (int fi = 0; fi < 4; ++fi) \
            _Pragma("unroll") \
            for (int reg = 0; reg < 4; ++reg) { \
                float p = __builtin_amdgcn_exp2f(s[fi][reg]); \
                s[fi][reg] = p; sm += p; \
            } \
        lsum[j] += sm; \
        unsigned wv[4][2]; \
        _Pragma("unroll") \
        for (int fi = 0; fi < 4; ++fi) { \
            asm("v_cvt_pk_bf16_f32 %0, %1, %2" : "=v"(wv[fi][0]) : "v"(s[fi][0]), "v"(s[fi][1])); \
            asm("v_cvt_pk_bf16_f32 %0, %1, %2" : "=v"(wv[fi][1]) : "v"(s[fi][2]), "v"(s[fi][3])); \
        } \
        uint2v r0 = __builtin_amdgcn_permlane16_swap(wv[0][0], wv[1][0], false, false); \
        uint2v r1 = __builtin_amdgcn_permlane16_swap(wv[0][1], wv[1][1], false, false); \
        uint2v r2 = __builtin_amdgcn_permlane16_swap(wv[2][0], wv[3][0], false, false); \
        uint2v r3 = __builtin_amdgcn_permlane16_swap(wv[2][1], wv[3][1], false, false); \
        union { unsigned uu[4]; bf16x8 vv; } p0, p1; \
        p0.uu[0] = r0[0]; p0.uu[1] = r1[0]; p0.uu[2] = r0[1]; p0.uu[3] = r1[1]; \
        p1.uu[0] = r2[0]; p1.uu[1] = r3[0]; p1.uu[2] = r2[1]; p1.uu[3] = r3[1]; \
        const unsigned vA = (VCA) + o0, vB = (VCA) + o1; \
        bf16x8 w0a, w0b, w1a, w1b; \
        __builtin_amdgcn_sched_barrier(0); \
        asm volatile( \
            "ds_read_b128 %0, %4 offset:0\n\t" \
            "ds_read_b128 %1, %5 offset:0\n\t" \
            "ds_read_b128 %2, %4 offset:2048\n\t" \
            "ds_read_b128 %3, %5 offset:2048\n\t" \
            "s_waitcnt lgkmcnt(0)" \
            : "=&v"(w0a), "=&v"(w0b), "=&v"(w1a), "=&v"(w1b) \
            : "v"(vA), "v"(vB)); \
        __builtin_amdgcn_sched_barrier(0); \
        oacc[j][0] = __builtin_amdgcn_mfma_f32_16x16x32_bf16(w0a, p0.vv, oacc[j][0], 0, 0, 0); \
        oacc[j][0] = __builtin_amdgcn_mfma_f32_16x16x32_bf16(w0b, p1.vv, oacc[j][0], 0, 0, 0); \
        oacc[j][1] = __builtin_amdgcn_mfma_f32_16x16x32_bf16(w1a, p0.vv, oacc[j][1], 0, 0, 0); \
        oacc[j][1] = __builtin_amdgcn_mfma_f32_16x16x32_bf16(w1b, p1.vv, oacc[j][1], 0, 0, 0); \
        bf16x8 w2a, w2b, w3a, w3b; \
        asm volatile( \
            "ds_read_b128 %0, %4 offset:4096\n\t" \
            "ds_read_b128 %1, %5 offset:4096\n\t" \
            "ds_read_b128 %2, %4 offset:6144\n\t" \
            "ds_read_b128 %3, %5 offset:6144\n\t" \
            "s_waitcnt lgkmcnt(0)" \
            : "=&v"(w2a), "=&v"(w2b), "=&v"(w3a), "=&v"(w3b) \
            : "v"(vA), "v"(vB)); \
        __builtin_amdgcn_sched_barrier(0); \
        oacc[j][2] = __builtin_amdgcn_mfma_f32_16x16x32_bf16(w2a, p0.vv, oacc[j][2], 0, 0, 0); \
        oacc[j][2] = __builtin_amdgcn_mfma_f32_16x16x32_bf16(w2b, p1.vv, oacc[j][2], 0, 0, 0); \
        oacc[j][3] = __builtin_amdgcn_mfma_f32_16x16x32_bf16(w3a, p0.vv, oacc[j][3], 0, 0, 0); \
        oacc[j][3] = __builtin_amdgcn_mfma_f32_16x16x32_bf16(w3b, p1.vv, oacc[j][3], 0, 0, 0); \
      } \
    } \
    asm volatile("s_waitcnt vmcnt(0)" ::: "memory"); \
    __syncthreads(); \
} while (0)

    bool flip = false;
    for (int kt = ktlo; kt < kthi; ++kt) {
        if (!flip) { ATT_TILE(&Vs[1][0], &Ks[1][0], vb0, kb0); }
        else       { ATT_TILE(&Vs[0][0], &Ks[0][0], vb1, kb1); }
        flip = !flip;
    }
#undef ATT_TILE

    if (g < 4) {
        // single-chunk: cross-quad l reduction, scale, store bf16 directly
        const int b = bh >> 4, h = bh & 15;
        #pragma unroll
        for (int j = 0; j < 2; ++j) {
            float l = lsum[j];
            l += __shfl_xor(l, 16);
            l += __shfl_xor(l, 32);
            float rl = 1.0f / l;
            int q = qw + j * 16 + l16;
            #pragma unroll
            for (int di = 0; di < 4; ++di) {
                union { bf16_t hh[4]; unsigned long long u64; } ok;
                #pragma unroll
                for (int reg = 0; reg < 4; ++reg) ok.hh[reg] = (bf16_t)(oacc[j][di][reg] * rl);
                int d = di * 16 + quad * 4;
                *(unsigned long long*)(O + ((size_t)b * T_SEQ + q) * D_MODEL + h * DKD + d) = ok.u64;
            }
        }
    } else {
        // partial: raw fp32 oacc + per-lane lsum to workspace
        const size_t slot = (size_t)bh * 36 + po + c;
        float* op = Opart + slot * 8192 + (size_t)w * 2048;
        #pragma unroll
        for (int j = 0; j < 2; ++j) {
            Lpart[slot * 512 + w * 128 + j * 64 + lane] = lsum[j];
            #pragma unroll
            for (int di = 0; di < 4; ++di)
                *(f32x4*)(op + ((size_t)(j * 4 + di) * 64 + lane) * 4) = oacc[j][di];
        }
    }
}

// ---------------- combine: O = (sum_c O_c) / (sum_c l_c), q rows [512, 2048) ----------------
__global__ __launch_bounds__(256) void combine_kernel(
    const float* __restrict__ Opart, const float* __restrict__ Lpart, bf16_t* __restrict__ O)
{
    const int bh = blockIdx.x;
    const int g = 4 + blockIdx.y;            // 4..15
    const int C = (g + 4) >> 2;              // chunks for this g
    int po0 = 0;
    for (int gg = 4; gg < g; ++gg) po0 += (gg + 4) >> 2;
    const int t = threadIdx.x;
    const int ql = t >> 3;                   // 0..31 local query
    const int d0 = (t & 7) * 8;              // 0,8,...,56
    const int j = ql >> 4, l16 = ql & 15;
    const int di = d0 >> 4;
    const int quad0 = (d0 & 15) >> 2;        // 0 or 2
    const int b = bh >> 4, h = bh & 15;
    const size_t sb = (size_t)bh * 36 + po0;

    for (int w = 0; w < 4; ++w) {
        float l = 0.f;
        for (int cc = 0; cc < C; ++cc) {
            const float* L = Lpart + (sb + cc) * 512 + w * 128 + j * 64 + l16;
            #pragma unroll
            for (int q = 0; q < 4; ++q) l += L[q * 16];
        }
        const float rl = 1.0f / l;
        union { bf16_t hh[8]; bf16x8 vv; } ov;
        #pragma unroll
        for (int g2 = 0; g2 < 2; ++g2) {
            const int off = ((j * 4 + di) * 64 + (quad0 + g2) * 16 + l16) * 4;
            f32x4 acc = {0.f, 0.f, 0.f, 0.f};
            for (int cc = 0; cc < C; ++cc)
                acc += *(const f32x4*)(Opart + (sb + cc) * 8192 + (size_t)w * 2048 + off);
            #pragma unroll
            for (int reg = 0; reg < 4; ++reg)
                ov.hh[g2 * 4 + reg] = (bf16_t)(acc[reg] * rl);
        }
        const int q = g * 128 + w * 32 + ql;
        *(bf16x8*)(O + ((size_t)b * T_SEQ + q) * D_MODEL + h * DKD + d0) = ov.vv;
    }
}

extern "C" void kernel_launch(void* const* d_in, const int* in_sizes, int n_in,
                              void* d_out, int out_size, void* d_ws, size_t ws_size,
                              hipStream_t stream)
{
    const float* x  = (const float*)d_in[0];
    const float* wq = (const float*)d_in[1];
    const float* wk = (const float*)d_in[2];
    const float* wv = (const float*)d_in[3];
    const float* wo = (const float*)d_in[4];
    float* out = (float*)d_out;

    char* ws = (char*)d_ws;
    size_t off = 0;
    auto alloc = [&](size_t bytes) -> void* {
        void* p = ws + off; off += (bytes + 255) & ~(size_t)255; return p;
    };
    bf16_t* xb   = (bf16_t*)alloc((size_t)X_ELEMS * 2);
    bf16_t* wqb  = (bf16_t*)alloc((size_t)W_ELEMS * 2);
    bf16_t* wkb  = (bf16_t*)alloc((size_t)W_ELEMS * 2);
    bf16_t* wvb  = (bf16_t*)alloc((size_t)W_ELEMS * 2);
    bf16_t* wob  = (bf16_t*)alloc((size_t)W_ELEMS * 2);
    bf16_t* qb   = (bf16_t*)alloc((size_t)X_ELEMS * 2);
    bf16_t* kb   = (bf16_t*)alloc((size_t)X_ELEMS * 2);
    bf16_t* vtb  = (bf16_t*)alloc((size_t)X_ELEMS * 2);
    bf16_t* ob   = (bf16_t*)alloc((size_t)X_ELEMS * 2);
    float*  cost = (float*)alloc((size_t)T_SEQ * 32 * 4);
    float*  sint = (float*)alloc((size_t)T_SEQ * 32 * 4);
    float*  opart = (float*)alloc((size_t)32 * 36 * 8192 * 4);  // 1152 slots x 4w x 32q x 64d fp32
    float*  lpart = (float*)alloc((size_t)32 * 36 * 512 * 4);   // 1152 slots x 4w x 2j x 64 lanes

    // convert (8192) + rope (256) fused into one launch
    convert_kernel<<<8448, 256, 0, stream>>>(x, wq, wk, wv, wo, xb, wqb, wkb, wvb, wob,
                                             cost, sint);
    gemm_fused<<<dim3(32, 8, 3), 256, 0, stream>>>(xb, wqb, wkb, wvb, qb, kb, vtb, cost, sint, nullptr, 0);
    attn_kernel<<<dim3(32, 40), 256, 0, stream>>>(qb, kb, vtb, ob, opart, lpart);
    combine_kernel<<<dim3(32, 12), 256, 0, stream>>>(opart, lpart, ob);
    // out-proj: 64x128 tiles -> 512 blocks = 2 blocks/CU
    out_proj<<<dim3(64, 8), 256, 0, stream>>>(ob, wob, out);
}